// Round 6
// baseline (448.030 us; speedup 1.0000x reference)
//
#include <hip/hip_runtime.h>
#include <hip/hip_bf16.h>

#define B_ 256
#define D_ 2048
#define N_ 30000
#define INV_TEMP 20.0f
#define MOM 0.2f
#define EPSF 1e-12f
#define BN 48
#define KC 64
#define NT 625   // 30000 / 48
#define NK 32    // D_ / KC
#define NBL 40   // kloss1 blocks
#define TPB 16   // tiles per kloss1 block (40*16 >= 625)

typedef __attribute__((ext_vector_type(8))) short bf16x8;
typedef __attribute__((ext_vector_type(4))) float f32x4;

__device__ __forceinline__ unsigned short f2bf(float f) {
  union { float f; unsigned int u; } v; v.f = f;
  unsigned int u = v.u;
  unsigned int r = (u + 0x7fffu + ((u >> 16) & 1u)) >> 16;
  return (unsigned short)r;
}

__device__ __forceinline__ float blockReduceSum256(float v) {
  __shared__ float red[4];
  #pragma unroll
  for (int m = 32; m >= 1; m >>= 1) v += __shfl_xor(v, m, 64);
  int lane = threadIdx.x & 63, w = threadIdx.x >> 6;
  __syncthreads();
  if (lane == 0) red[w] = v;
  __syncthreads();
  return red[0] + red[1] + red[2] + red[3];
}

// ---------------- Kernel A: normalize inputs, emit fp32 + bf16 copies -------
__global__ __launch_bounds__(256) void knorm(const float* __restrict__ in,
                                             float* __restrict__ x,
                                             unsigned short* __restrict__ xbf) {
  int b = blockIdx.x, t = threadIdx.x;
  const float* row = in + (size_t)b * D_;
  float vals[8]; float ss = 0.f;
  #pragma unroll
  for (int i = 0; i < 8; i++) { float f = row[t + i * 256]; vals[i] = f; ss += f * f; }
  float tot = blockReduceSum256(ss);
  float inv = 1.0f / (sqrtf(tot) + EPSF);
  #pragma unroll
  for (int i = 0; i < 8; i++) {
    float xv = vals[i] * inv;
    x[(size_t)b * D_ + t + i * 256] = xv;
    xbf[(size_t)b * D_ + t + i * 256] = f2bf(xv);
  }
}

// ---------------- Kernel B: 2-deep reg-ride pipelined GEMM + copy -----------
// BN=48, BM=256, 4 waves. Double-buffered LDS; regs hold tiles s and s+1;
// loads for tile s+2 issued at step s. Raw s_barrier + lgkmcnt(0) only —
// global loads/stores ride across barriers (no vmcnt(0) drain in loop).
__global__ __launch_bounds__(256, 2) void kmain(const float* __restrict__ feats,
                                                const unsigned short* __restrict__ xbf,
                                                float* __restrict__ outp,
                                                float* __restrict__ pmax,
                                                float* __restrict__ psum) {
  __shared__ __align__(16) unsigned short xs[2][16384];  // 2 x 256rows x 64cols bf16
  __shared__ __align__(16) unsigned short fs[2][3072];   // 2 x 48rows x 64cols bf16
  int tid = threadIdx.x, wave = tid >> 6, lane = tid & 63;
  int n0 = blockIdx.x * BN;
  int q = lane >> 4, lr = lane & 15;
  int sl = (lane & 48) | ((lane + 1) & 15);   // next-c lane within 16-group

  // xs staging map: fi = tid + i*256 -> row b=fi>>3, 16B chunk g=fi&7
  // fs staging map: fi = tid + i*256 -> row n=fi>>4, float4 chunk c=fi&15
  int fn[3], fc[3];
  #pragma unroll
  for (int i = 0; i < 3; i++) { int fi = tid + i * 256; fn[i] = fi >> 4; fc[i] = fi & 15; }

  uint4  xv[2][8];
  float4 fv[2][3];

  // prologue: load tiles 0 (set 0) and 1 (set 1)
  #pragma unroll
  for (int set = 0; set < 2; set++) {
    int kl = set * KC;
    #pragma unroll
    for (int i = 0; i < 8; i++) {
      int fi = tid + i * 256, b = fi >> 3, g = fi & 7;
      xv[set][i] = *(const uint4*)(xbf + (size_t)b * D_ + kl + g * 8);
    }
    #pragma unroll
    for (int i = 0; i < 3; i++)
      fv[set][i] = *(const float4*)(feats + (size_t)(n0 + fn[i]) * D_ + kl + 4 * fc[i]);
  }

  f32x4 acc[4][3];
  #pragma unroll
  for (int i = 0; i < 4; i++)
    #pragma unroll
    for (int j = 0; j < 3; j++) acc[i][j] = f32x4{0.f, 0.f, 0.f, 0.f};

  for (int t = 0; t < NK; t += 2) {
    #pragma unroll
    for (int ph = 0; ph < 2; ph++) {
      int s = t + ph;
      // --- phase 1: ds_write tile s (vmcnt waits inserted here by compiler,
      //              ~2 K-steps after issue -> latency hidden) ---
      #pragma unroll
      for (int i = 0; i < 8; i++) {
        int fi = tid + i * 256, b = fi >> 3, g = fi & 7;
        int byte = b * 128 + ((g * 16) ^ ((b & 7) << 4));
        *(uint4*)((char*)&xs[ph][0] + byte) = xv[ph][i];
      }
      #pragma unroll
      for (int i = 0; i < 3; i++) {
        union { __hip_bfloat162 h2[2]; uint2 u8; } pk;
        pk.h2[0] = __float22bfloat162_rn(make_float2(fv[ph][i].x, fv[ph][i].y));
        pk.h2[1] = __float22bfloat162_rn(make_float2(fv[ph][i].z, fv[ph][i].w));
        int byte = fn[i] * 128 + ((8 * fc[i]) ^ ((fn[i] & 7) << 4));
        *(uint2*)((char*)&fs[ph][0] + byte) = pk.u8;
      }
      // --- phase 2: fused copy-out of tile s (fire-and-forget stores) ---
      #pragma unroll
      for (int i = 0; i < 3; i++) {
        float4 v = fv[ph][i];
        float nx = __shfl(v.x, sl, 64);
        float ny = __shfl(v.y, sl, 64);
        float nz = __shfl(v.z, sl, 64);
        size_t rb = (size_t)(n0 + fn[i]) * D_ + s * KC;  // out-absolute (+1 folded)
        int c = fc[i];
        if (c < 15) *(float4*)(outp + rb + 4 * c + 4) = make_float4(v.w, nx, ny, nz);
        else        outp[rb + 64] = v.w;
        if (c == 0) { outp[rb + 1] = v.x; outp[rb + 2] = v.y; outp[rb + 3] = v.z; }
      }
      // --- phase 3: issue loads for tile s+2 into this set ---
      if (s + 2 < NK) {
        int kl = (s + 2) * KC;
        #pragma unroll
        for (int i = 0; i < 8; i++) {
          int fi = tid + i * 256, b = fi >> 3, g = fi & 7;
          xv[ph][i] = *(const uint4*)(xbf + (size_t)b * D_ + kl + g * 8);
        }
        #pragma unroll
        for (int i = 0; i < 3; i++)
          fv[ph][i] = *(const float4*)(feats + (size_t)(n0 + fn[i]) * D_ + kl + 4 * fc[i]);
      }
      // --- phase 4: LDS-only fence (no vmcnt drain!) ---
      __builtin_amdgcn_sched_barrier(0);
      asm volatile("s_waitcnt lgkmcnt(0)" ::: "memory");
      __builtin_amdgcn_s_barrier();
      __builtin_amdgcn_sched_barrier(0);
      // --- phase 5: compute tile s from buf[ph] ---
      #pragma unroll
      for (int ks = 0; ks < 2; ks++) {
        int g = ks * 4 + q;
        bf16x8 a[4], bb[3];
        #pragma unroll
        for (int mi = 0; mi < 4; mi++) {
          int row = wave * 64 + mi * 16 + lr;
          a[mi] = *(const bf16x8*)((char*)&xs[ph][0] + row * 128 + ((g * 16) ^ ((row & 7) << 4)));
        }
        #pragma unroll
        for (int ni = 0; ni < 3; ni++) {
          int row = ni * 16 + lr;
          bb[ni] = *(const bf16x8*)((char*)&fs[ph][0] + row * 128 + ((g * 16) ^ ((row & 7) << 4)));
        }
        #pragma unroll
        for (int mi = 0; mi < 4; mi++)
          #pragma unroll
          for (int ni = 0; ni < 3; ni++)
            acc[mi][ni] = __builtin_amdgcn_mfma_f32_16x16x32_bf16(a[mi], bb[ni], acc[mi][ni], 0, 0, 0);
      }
    }
  }

  // ---- epilogue: per-row partial max/sumexp over this block's 48 cols ----
  #pragma unroll
  for (int mi = 0; mi < 4; mi++) {
    #pragma unroll
    for (int r = 0; r < 4; r++) {
      float v0 = acc[mi][0][r] * INV_TEMP;
      float v1 = acc[mi][1][r] * INV_TEMP;
      float v2 = acc[mi][2][r] * INV_TEMP;
      float mx = fmaxf(fmaxf(v0, v1), v2);
      #pragma unroll
      for (int m = 8; m >= 1; m >>= 1) mx = fmaxf(mx, __shfl_xor(mx, m, 64));
      float s = __expf(v0 - mx) + __expf(v1 - mx) + __expf(v2 - mx);
      #pragma unroll
      for (int m = 8; m >= 1; m >>= 1) s += __shfl_xor(s, m, 64);
      if (lr == 0) {
        int row = wave * 64 + mi * 16 + q * 4 + r;
        pmax[(size_t)blockIdx.x * 256 + row] = mx;
        psum[(size_t)blockIdx.x * 256 + row] = s;
      }
    }
  }
}

// ---------------- Kernel C: exact fp32 target logits ------------------------
__global__ __launch_bounds__(256) void ktdot(const float* __restrict__ feats,
                                             const float* __restrict__ x,
                                             const int* __restrict__ tgt,
                                             float* __restrict__ tdot) {
  int b = blockIdx.x, t = threadIdx.x;
  int y = tgt[b];
  const float* fr = feats + (size_t)y * D_;
  const float* xr = x + (size_t)b * D_;
  float s = 0.f;
  #pragma unroll
  for (int i = 0; i < 8; i++) s += fr[t + i * 256] * xr[t + i * 256];
  float tot = blockReduceSum256(s);
  if (t == 0) tdot[b] = tot * INV_TEMP;
}

// ---------------- Kernel D1: coalesced tile-range combine (40 blocks) -------
__global__ __launch_bounds__(256) void kloss1(const float* __restrict__ pmax,
                                              const float* __restrict__ psum,
                                              float* __restrict__ pm2,
                                              float* __restrict__ ps2) {
  int b = threadIdx.x, j = blockIdx.x;
  float m = -INFINITY, s = 0.f;
  #pragma unroll 4
  for (int i = 0; i < TPB; i++) {
    int tile = j * TPB + i;
    if (tile >= NT) break;
    float mt = pmax[(size_t)tile * 256 + b];
    float st = psum[(size_t)tile * 256 + b];
    if (mt > m) { s = s * __expf(m - mt) + st; m = mt; }
    else        { s += st * __expf(mt - m); }
  }
  pm2[j * 256 + b] = m;
  ps2[j * 256 + b] = s;
}

// ---------------- Kernel D2: final combine + mean -> loss -------------------
__global__ __launch_bounds__(256) void kloss2(const float* __restrict__ pm2,
                                              const float* __restrict__ ps2,
                                              const float* __restrict__ tdot,
                                              float* __restrict__ out) {
  int b = threadIdx.x;
  float m = -INFINITY, s = 0.f;
  for (int j = 0; j < NBL; j++) {
    float mt = pm2[j * 256 + b];
    float st = ps2[j * 256 + b];
    float M = fmaxf(m, mt);
    s = s * __expf(m - M) + st * __expf(mt - M);
    m = M;
  }
  float lb = m + logf(s) - tdot[b];
  float tot = blockReduceSum256(lb);
  if (b == 0) out[0] = tot * (1.0f / 256.0f);
}

// ---------------- Kernel E: momentum update (first-occurrence chains) -------
__global__ __launch_bounds__(256) void kupdate(const float* __restrict__ feats,
                                               const float* __restrict__ x,
                                               const int* __restrict__ tgt,
                                               float* __restrict__ outF) {
  int b = blockIdx.x, t = threadIdx.x;
  int y = tgt[b];
  for (int i = 0; i < b; i++) if (tgt[i] == y) return;  // block-uniform exit
  float f[8];
  #pragma unroll
  for (int i = 0; i < 8; i++) f[i] = feats[(size_t)y * D_ + t + i * 256];
  for (int b2 = b; b2 < B_; b2++) {
    if (tgt[b2] != y) continue;  // block-uniform
    float ss = 0.f;
    #pragma unroll
    for (int i = 0; i < 8; i++) {
      f[i] = MOM * f[i] + (1.0f - MOM) * x[(size_t)b2 * D_ + t + i * 256];
      ss += f[i] * f[i];
    }
    float tot = blockReduceSum256(ss);
    float inv = 1.0f / (sqrtf(tot) + EPSF);
    #pragma unroll
    for (int i = 0; i < 8; i++) f[i] *= inv;
  }
  #pragma unroll
  for (int i = 0; i < 8; i++) outF[(size_t)y * D_ + t + i * 256] = f[i];
}

extern "C" void kernel_launch(void* const* d_in, const int* in_sizes, int n_in,
                              void* d_out, int out_size, void* d_ws, size_t ws_size,
                              hipStream_t stream) {
  const float* inputs = (const float*)d_in[0];
  const float* feats  = (const float*)d_in[1];
  const int*   tgt    = (const int*)d_in[2];
  float* out  = (float*)d_out;
  float* outF = out + 1;  // new_features, N_ x D_

  char* ws = (char*)d_ws;
  float*          x    = (float*)ws;                                   // 2 MB
  unsigned short* xbf  = (unsigned short*)(ws + (size_t)B_ * D_ * 4);  // 1 MB
  float*          pmax = (float*)(ws + (size_t)B_ * D_ * 4 + (size_t)B_ * D_ * 2);
  float*          psum = pmax + (size_t)NT * 256;
  float*          pm2  = psum + (size_t)NT * 256;
  float*          ps2  = pm2 + (size_t)NBL * 256;
  float*          tdot = ps2 + (size_t)NBL * 256;

  hipLaunchKernelGGL(knorm,   dim3(B_),  dim3(256), 0, stream, inputs, x, xbf);
  hipLaunchKernelGGL(kmain,   dim3(NT),  dim3(256), 0, stream, feats, xbf, out, pmax, psum);
  hipLaunchKernelGGL(ktdot,   dim3(B_),  dim3(256), 0, stream, feats, x, tgt, tdot);
  hipLaunchKernelGGL(kloss1,  dim3(NBL), dim3(256), 0, stream, pmax, psum, pm2, ps2);
  hipLaunchKernelGGL(kloss2,  dim3(1),   dim3(256), 0, stream, pm2, ps2, tdot, out);
  hipLaunchKernelGGL(kupdate, dim3(B_),  dim3(256), 0, stream, feats, x, tgt, outF);
}

// Round 7
// 343.050 us; speedup vs baseline: 1.3060x; 1.3060x over previous
//
#include <hip/hip_runtime.h>
#include <hip/hip_bf16.h>

#define B_ 256
#define D_ 2048
#define N_ 30000
#define INV_TEMP 20.0f
#define MOM 0.2f
#define EPSF 1e-12f
#define BM 128
#define BN 48
#define KC 64
#define NT 625   // 30000 / 48 N-tiles
#define NK 32    // D_ / KC
#define NBL 40   // kloss1 blocks
#define TPB 16   // tiles per kloss1 block

typedef __attribute__((ext_vector_type(8))) short bf16x8;
typedef __attribute__((ext_vector_type(4))) float f32x4;

__device__ __forceinline__ unsigned short f2bf(float f) {
  union { float f; unsigned int u; } v; v.f = f;
  unsigned int u = v.u;
  unsigned int r = (u + 0x7fffu + ((u >> 16) & 1u)) >> 16;
  return (unsigned short)r;
}

__device__ __forceinline__ float blockReduceSum256(float v) {
  __shared__ float red[4];
  #pragma unroll
  for (int m = 32; m >= 1; m >>= 1) v += __shfl_xor(v, m, 64);
  int lane = threadIdx.x & 63, w = threadIdx.x >> 6;
  __syncthreads();
  if (lane == 0) red[w] = v;
  __syncthreads();
  return red[0] + red[1] + red[2] + red[3];
}

// ---------------- Kernel A: normalize inputs, emit fp32 + bf16 copies -------
__global__ __launch_bounds__(256) void knorm(const float* __restrict__ in,
                                             float* __restrict__ x,
                                             unsigned short* __restrict__ xbf) {
  int b = blockIdx.x, t = threadIdx.x;
  const float* row = in + (size_t)b * D_;
  float vals[8]; float ss = 0.f;
  #pragma unroll
  for (int i = 0; i < 8; i++) { float f = row[t + i * 256]; vals[i] = f; ss += f * f; }
  float tot = blockReduceSum256(ss);
  float inv = 1.0f / (sqrtf(tot) + EPSF);
  #pragma unroll
  for (int i = 0; i < 8; i++) {
    float xv = vals[i] * inv;
    x[(size_t)b * D_ + t + i * 256] = xv;
    xbf[(size_t)b * D_ + t + i * 256] = f2bf(xv);
  }
}

// ---------------- Kernel B: 1-barrier/step pipelined GEMM + fused copy ------
// BM=128 (mb=blockIdx&1), BN=48 (nb=blockIdx>>1). 4 waves, wave owns 32 rows.
// Regs hold tile t+1; LDS double-buffered; per-step barrier is lgkm-only so
// global loads (tile t+1) and outF stores ride across it.
__global__ __launch_bounds__(256, 3) void kmain(const float* __restrict__ feats,
                                                const unsigned short* __restrict__ xbf,
                                                float* __restrict__ outp,
                                                float* __restrict__ pmax,
                                                float* __restrict__ psum) {
  __shared__ __align__(16) unsigned short xs[2][8192];  // 2 x 128rows x 64cols bf16
  __shared__ __align__(16) unsigned short fs[2][3072];  // 2 x 48rows x 64cols bf16
  int tid = threadIdx.x, wave = tid >> 6, lane = tid & 63;
  int mb = blockIdx.x & 1, nb = blockIdx.x >> 1;
  int n0 = nb * BN;
  int q = lane >> 4, lr = lane & 15;
  int sl = (lane & 48) | ((lane + 1) & 15);   // next-chunk lane within 16-group

  // xs map: fi = tid + i*256 (i<4) -> row b=fi>>3 in [0,128), 16B chunk g=fi&7
  // fs map: fi = tid + i*256 (i<3) -> row n=fi>>4 in [0,48), float4 chunk c=fi&15
  int fn[3], fc[3];
  #pragma unroll
  for (int i = 0; i < 3; i++) { int fi = tid + i * 256; fn[i] = fi >> 4; fc[i] = fi & 15; }

  uint4  xv[4];
  float4 fv[3];

  // prologue: load tile 0 into regs
  #pragma unroll
  for (int i = 0; i < 4; i++) {
    int fi = tid + i * 256, b = fi >> 3, g = fi & 7;
    xv[i] = *(const uint4*)(xbf + (size_t)(mb * BM + b) * D_ + g * 8);
  }
  #pragma unroll
  for (int i = 0; i < 3; i++)
    fv[i] = *(const float4*)(feats + (size_t)(n0 + fn[i]) * D_ + 4 * fc[i]);

  f32x4 acc[2][3];
  #pragma unroll
  for (int i = 0; i < 2; i++)
    #pragma unroll
    for (int j = 0; j < 3; j++) acc[i][j] = f32x4{0.f, 0.f, 0.f, 0.f};

  for (int t = 0; t < NK; t++) {
    int cur = t & 1;
    unsigned short* xc = &xs[cur][0];
    unsigned short* fcb = &fs[cur][0];
    // --- phase A: ds_write tile t (from regs) + fused copy-out (from regs) ---
    #pragma unroll
    for (int i = 0; i < 4; i++) {
      int fi = tid + i * 256, b = fi >> 3, g = fi & 7;
      int byte = b * 128 + ((g * 16) ^ ((b & 7) << 4));
      *(uint4*)((char*)xc + byte) = xv[i];
    }
    #pragma unroll
    for (int i = 0; i < 3; i++) {
      union { __hip_bfloat162 h2[2]; uint2 u8; } pk;
      pk.h2[0] = __float22bfloat162_rn(make_float2(fv[i].x, fv[i].y));
      pk.h2[1] = __float22bfloat162_rn(make_float2(fv[i].z, fv[i].w));
      int byte = fn[i] * 128 + ((8 * fc[i]) ^ ((fn[i] & 7) << 4));
      *(uint2*)((char*)fcb + byte) = pk.u8;
    }
    if (mb == 0) {
      #pragma unroll
      for (int i = 0; i < 3; i++) {
        float4 v = fv[i];
        float nx = __shfl(v.x, sl, 64);
        float ny = __shfl(v.y, sl, 64);
        float nz = __shfl(v.z, sl, 64);
        size_t rb = (size_t)(n0 + fn[i]) * D_ + t * KC;  // out-absolute (+1 folded)
        int c = fc[i];
        if (c < 15) *(float4*)(outp + rb + 4 * c + 4) = make_float4(v.w, nx, ny, nz);
        else        outp[rb + 64] = v.w;
        if (c == 0) { outp[rb + 1] = v.x; outp[rb + 2] = v.y; outp[rb + 3] = v.z; }
      }
    }
    // --- phase B: issue loads for tile t+1 (ride across the barrier) ---
    if (t + 1 < NK) {
      int kl = (t + 1) * KC;
      #pragma unroll
      for (int i = 0; i < 4; i++) {
        int fi = tid + i * 256, b = fi >> 3, g = fi & 7;
        xv[i] = *(const uint4*)(xbf + (size_t)(mb * BM + b) * D_ + kl + g * 8);
      }
      #pragma unroll
      for (int i = 0; i < 3; i++)
        fv[i] = *(const float4*)(feats + (size_t)(n0 + fn[i]) * D_ + kl + 4 * fc[i]);
    }
    // --- phase C: lgkm-only fence + barrier (NO vmcnt drain) ---
    __builtin_amdgcn_sched_barrier(0);
    asm volatile("s_waitcnt lgkmcnt(0)" ::: "memory");
    __builtin_amdgcn_s_barrier();
    __builtin_amdgcn_sched_barrier(0);
    // --- phase D: compute tile t ---
    #pragma unroll
    for (int ks = 0; ks < 2; ks++) {
      int g = ks * 4 + q;
      bf16x8 a[2], bb[3];
      #pragma unroll
      for (int mi = 0; mi < 2; mi++) {
        int row = wave * 32 + mi * 16 + lr;
        a[mi] = *(const bf16x8*)((char*)xc + row * 128 + ((g * 16) ^ ((row & 7) << 4)));
      }
      #pragma unroll
      for (int ni = 0; ni < 3; ni++) {
        int row = ni * 16 + lr;
        bb[ni] = *(const bf16x8*)((char*)fcb + row * 128 + ((g * 16) ^ ((row & 7) << 4)));
      }
      #pragma unroll
      for (int mi = 0; mi < 2; mi++)
        #pragma unroll
        for (int ni = 0; ni < 3; ni++)
          acc[mi][ni] = __builtin_amdgcn_mfma_f32_16x16x32_bf16(a[mi], bb[ni], acc[mi][ni], 0, 0, 0);
    }
  }

  // ---- epilogue: per-row partial max/sumexp over this block's 48 cols ----
  #pragma unroll
  for (int mi = 0; mi < 2; mi++) {
    #pragma unroll
    for (int r = 0; r < 4; r++) {
      float v0 = acc[mi][0][r] * INV_TEMP;
      float v1 = acc[mi][1][r] * INV_TEMP;
      float v2 = acc[mi][2][r] * INV_TEMP;
      float mx = fmaxf(fmaxf(v0, v1), v2);
      #pragma unroll
      for (int m = 8; m >= 1; m >>= 1) mx = fmaxf(mx, __shfl_xor(mx, m, 64));
      float s = __expf(v0 - mx) + __expf(v1 - mx) + __expf(v2 - mx);
      #pragma unroll
      for (int m = 8; m >= 1; m >>= 1) s += __shfl_xor(s, m, 64);
      if (lr == 0) {
        int row = mb * BM + wave * 32 + mi * 16 + q * 4 + r;
        pmax[(size_t)nb * 256 + row] = mx;
        psum[(size_t)nb * 256 + row] = s;
      }
    }
  }
}

// ---------------- Kernel C: exact fp32 target logits ------------------------
__global__ __launch_bounds__(256) void ktdot(const float* __restrict__ feats,
                                             const float* __restrict__ x,
                                             const int* __restrict__ tgt,
                                             float* __restrict__ tdot) {
  int b = blockIdx.x, t = threadIdx.x;
  int y = tgt[b];
  const float* fr = feats + (size_t)y * D_;
  const float* xr = x + (size_t)b * D_;
  float s = 0.f;
  #pragma unroll
  for (int i = 0; i < 8; i++) s += fr[t + i * 256] * xr[t + i * 256];
  float tot = blockReduceSum256(s);
  if (t == 0) tdot[b] = tot * INV_TEMP;
}

// ---------------- Kernel D1: coalesced tile-range combine (40 blocks) -------
__global__ __launch_bounds__(256) void kloss1(const float* __restrict__ pmax,
                                              const float* __restrict__ psum,
                                              float* __restrict__ pm2,
                                              float* __restrict__ ps2) {
  int b = threadIdx.x, j = blockIdx.x;
  float m = -INFINITY, s = 0.f;
  #pragma unroll 4
  for (int i = 0; i < TPB; i++) {
    int tile = j * TPB + i;
    if (tile >= NT) break;
    float mt = pmax[(size_t)tile * 256 + b];
    float st = psum[(size_t)tile * 256 + b];
    if (mt > m) { s = s * __expf(m - mt) + st; m = mt; }
    else        { s += st * __expf(mt - m); }
  }
  pm2[j * 256 + b] = m;
  ps2[j * 256 + b] = s;
}

// ---------------- Kernel D2: final combine + mean -> loss -------------------
__global__ __launch_bounds__(256) void kloss2(const float* __restrict__ pm2,
                                              const float* __restrict__ ps2,
                                              const float* __restrict__ tdot,
                                              float* __restrict__ out) {
  int b = threadIdx.x;
  float m = -INFINITY, s = 0.f;
  for (int j = 0; j < NBL; j++) {
    float mt = pm2[j * 256 + b];
    float st = ps2[j * 256 + b];
    float M = fmaxf(m, mt);
    s = s * __expf(m - M) + st * __expf(mt - M);
    m = M;
  }
  float lb = m + logf(s) - tdot[b];
  float tot = blockReduceSum256(lb);
  if (b == 0) out[0] = tot * (1.0f / 256.0f);
}

// ---------------- Kernel E: momentum update (first-occurrence chains) -------
__global__ __launch_bounds__(256) void kupdate(const float* __restrict__ feats,
                                               const float* __restrict__ x,
                                               const int* __restrict__ tgt,
                                               float* __restrict__ outF) {
  int b = blockIdx.x, t = threadIdx.x;
  int y = tgt[b];
  for (int i = 0; i < b; i++) if (tgt[i] == y) return;  // block-uniform exit
  float f[8];
  #pragma unroll
  for (int i = 0; i < 8; i++) f[i] = feats[(size_t)y * D_ + t + i * 256];
  for (int b2 = b; b2 < B_; b2++) {
    if (tgt[b2] != y) continue;  // block-uniform
    float ss = 0.f;
    #pragma unroll
    for (int i = 0; i < 8; i++) {
      f[i] = MOM * f[i] + (1.0f - MOM) * x[(size_t)b2 * D_ + t + i * 256];
      ss += f[i] * f[i];
    }
    float tot = blockReduceSum256(ss);
    float inv = 1.0f / (sqrtf(tot) + EPSF);
    #pragma unroll
    for (int i = 0; i < 8; i++) f[i] *= inv;
  }
  #pragma unroll
  for (int i = 0; i < 8; i++) outF[(size_t)y * D_ + t + i * 256] = f[i];
}

extern "C" void kernel_launch(void* const* d_in, const int* in_sizes, int n_in,
                              void* d_out, int out_size, void* d_ws, size_t ws_size,
                              hipStream_t stream) {
  const float* inputs = (const float*)d_in[0];
  const float* feats  = (const float*)d_in[1];
  const int*   tgt    = (const int*)d_in[2];
  float* out  = (float*)d_out;
  float* outF = out + 1;  // new_features, N_ x D_

  char* ws = (char*)d_ws;
  float*          x    = (float*)ws;                                   // 2 MB
  unsigned short* xbf  = (unsigned short*)(ws + (size_t)B_ * D_ * 4);  // 1 MB
  float*          pmax = (float*)(ws + (size_t)B_ * D_ * 4 + (size_t)B_ * D_ * 2);
  float*          psum = pmax + (size_t)NT * 256;
  float*          pm2  = psum + (size_t)NT * 256;
  float*          ps2  = pm2 + (size_t)NBL * 256;
  float*          tdot = ps2 + (size_t)NBL * 256;

  hipLaunchKernelGGL(knorm,   dim3(B_),      dim3(256), 0, stream, inputs, x, xbf);
  hipLaunchKernelGGL(kmain,   dim3(NT * 2),  dim3(256), 0, stream, feats, xbf, out, pmax, psum);
  hipLaunchKernelGGL(ktdot,   dim3(B_),      dim3(256), 0, stream, feats, x, tgt, tdot);
  hipLaunchKernelGGL(kloss1,  dim3(NBL),     dim3(256), 0, stream, pmax, psum, pm2, ps2);
  hipLaunchKernelGGL(kloss2,  dim3(1),       dim3(256), 0, stream, pm2, ps2, tdot, out);
  hipLaunchKernelGGL(kupdate, dim3(B_),      dim3(256), 0, stream, feats, x, tgt, outF);
}